// Round 2
// baseline (432.874 us; speedup 1.0000x reference)
//
#include <hip/hip_runtime.h>
#include <math.h>

#define OBS_DIM 115
#define N_AGENTS 11
#define ROW_F 1265                 // floats per gs row (5060 B)
#define ROWS_PER_WAVE 4
#define WAVES_PER_BLOCK 4
#define ROWS_PER_BLOCK (ROWS_PER_WAVE * WAVES_PER_BLOCK)   // 16
#define SLICE_F 1280               // staged floats per row: 5120 B, 16B-aligned window
// LDS = 16 * 5120 B = 80 KiB -> exactly 2 blocks/CU (8 waves/CU), full-stream staging.
// Row stride 1280 % 32 == 0 -> the 4 groups of a wave alias banks 4-way on compute
// reads; ~17 ds_reads/lane at 1.58x is noise vs the memory phase, so no pad
// (padding would break the 2-blocks/CU LDS fit).

typedef const __attribute__((address_space(1))) unsigned int gu32;
typedef __attribute__((address_space(3))) unsigned int lu32;

__global__ __launch_bounds__(256) void qmix_kernel(
    const float* __restrict__ q,    // [B, 11]
    const float* __restrict__ gs,   // [B, 1265]
    float* __restrict__ out,        // [B]
    int B)
{
    __shared__ float lds[ROWS_PER_BLOCK * SLICE_F];   // 81920 B

    const int tid  = threadIdx.x;
    const int wv   = tid >> 6;
    const int lane = tid & 63;
    const int rbase = blockIdx.x * ROWS_PER_BLOCK + wv * ROWS_PER_WAVE;

    // ---- stage: 4 full rows per wave, contiguous dwordx4 global->LDS ----
    // Window per row: floats [rr*1265 - (rr&3), +1280)  (16B-aligned source).
    // Needed columns end at 10*115+107 = 1257; shift<=3 -> max LDS idx 1260 < 1280.
    #pragma unroll
    for (int rl = 0; rl < ROWS_PER_WAVE; ++rl) {
        int rr = rbase + rl;
        if (rr >= B) rr = B - 1;
        const int shift = rr & 3;                       // (rr*5060)%16 == 4*(rr&3)
        const float* src = gs + ((size_t)rr * ROW_F - shift);
        float* dst = &lds[(wv * ROWS_PER_WAVE + rl) * SLICE_F];
        #pragma unroll
        for (int p = 0; p < 5; ++p) {
            // last pass of the global last row would overread 60 B past gs
            // (gs byte size is exactly page-aligned) -> exec-mask lanes >= 60;
            // lanes 0..59 still cover floats up to 1264 >= 1257+shift.
            const bool active = !(p == 4 && rr == B - 1 && lane >= 60);
            if (active) {
                __builtin_amdgcn_global_load_lds(
                    (gu32*)(src + p * 256 + lane * 4),
                    (lu32*)(dst + p * 256),
                    16, 0, 0);
            }
        }
    }

    // per-row compute assignment: group g of this wave = row rbase+g (own staged rows)
    const int g  = lane >> 4;
    const int s  = lane & 15;
    int rr = rbase + g;
    const bool row_ok = (rr < B);
    if (!row_ok) rr = B - 1;

    // q load issued while staging loads are still in flight (drained by same vmcnt)
    float qv = 0.0f;
    if (s < N_AGENTS) qv = q[(size_t)rr * N_AGENTS + s];

    // wave consumes only its own staged rows -> no barrier, just drain the LDS-DMA
    asm volatile("s_waitcnt vmcnt(0)" ::: "memory");

    const float* S = &lds[(wv * ROWS_PER_WAVE + g) * SLICE_F + (rr & 3)];

    const float bx = S[88], by = S[89], team = S[95];
    const float g0  = bx - 1.0f;
    const float bgd = sqrtf(g0 * g0 + by * by);
    const bool valid = (team != 0.0f) && (bgd > 0.19f) && (bgd < 0.99f);

    float dist = INFINITY;      // inactive lanes lose argmin
    float comb = -INFINITY;     // inactive lanes contribute exp()=0
    float gd = 0.0f;

    if (s < N_AGENTS) {
        // argmax over ID block cols 97..107 (first-max tie-break: strict >)
        const float* idb = S + s * OBS_DIM + 97;
        float best = idb[0]; int bi = 0;
        #pragma unroll
        for (int j = 1; j < 11; ++j) {
            float v = idb[j];
            if (v > best) { best = v; bi = j; }
        }
        const float px = S[s * OBS_DIM + 2 * bi];
        const float py = S[s * OBS_DIM + 2 * bi + 1];
        const float dx = px - bx, dy = py - by;
        dist = sqrtf(dx * dx + dy * dy);
        const float gx = px - 1.0f;
        gd = sqrtf(gx * gx + py * py);
    }

    // group argmin over dist (first-min tie-break: prefer lower index)
    int idx = s;
    float d = dist;
    #pragma unroll
    for (int o = 8; o >= 1; o >>= 1) {
        float d2 = __shfl_xor(d, o, 16);
        int   i2 = __shfl_xor(idx, o, 16);
        if (d2 < d || (d2 == d && i2 < idx)) { d = d2; idx = i2; }
    }

    if (s < N_AGENTS)
        comb = valid ? ((s == idx) ? 5.0f : 0.0f)
                     : 1.0f / (gd + 1e-6f);

    // group max of comb
    float m = comb;
    #pragma unroll
    for (int o = 8; o >= 1; o >>= 1)
        m = fmaxf(m, __shfl_xor(m, o, 16));

    // softmax denom + weighted q sum
    float w  = expf(comb - m);   // 0 for inactive lanes
    float wq = w * qv;
    #pragma unroll
    for (int o = 8; o >= 1; o >>= 1) {
        w  += __shfl_xor(w,  o, 16);
        wq += __shfl_xor(wq, o, 16);
    }

    if (s == 0 && row_ok)
        out[rr] = wq * (float)N_AGENTS / w;
}

extern "C" void kernel_launch(void* const* d_in, const int* in_sizes, int n_in,
                              void* d_out, int out_size, void* d_ws, size_t ws_size,
                              hipStream_t stream) {
    const float* q  = (const float*)d_in[0];   // agents_q  [128,512,11]
    const float* gs = (const float*)d_in[1];   // global_state [128,512,1265]
    float* out = (float*)d_out;                // [128,512,1] f32

    int B = in_sizes[0] / N_AGENTS;            // 65536
    int grid = (B + ROWS_PER_BLOCK - 1) / ROWS_PER_BLOCK;  // 4096
    qmix_kernel<<<grid, 256, 0, stream>>>(q, gs, out, B);
}

// Round 3
// 399.757 us; speedup vs baseline: 1.0828x; 1.0828x over previous
//
#include <hip/hip_runtime.h>
#include <math.h>

#define OBS_DIM 115
#define N_AGENTS 11
#define TPR 16                 // threads per row (11 active agent slots)
#define ROWS_PER_BLOCK 16      // 256 / TPR
// one thread per (row, agent-slot); shfl-based reductions within 16-lane groups.
// Round-3 note: this structure's demanded-line footprint (~29 x 128B lines/row,
// ~0.29 GB total) is within ~25% of the data-dependent minimum; LDS-staging
// variants (packed 4B DMA, full-row 16B DMA) both regressed (+10/+33 us) --
// the timed window is combined-HBM-bound (harness 1.326 GB re-poison fill +
// kernel reads at ~4.1 TB/s mixed), so extra staged bytes cost linearly and
// stream-shape does not matter.

__global__ __launch_bounds__(256) void qmix_kernel(
    const float* __restrict__ q,    // [B, 11]
    const float* __restrict__ gs,   // [B, 1265]
    float* __restrict__ out,        // [B]
    int B)
{
    const int tid = threadIdx.x;
    const int g   = tid >> 4;              // row group within block
    const int s   = tid & 15;              // agent slot 0..15 (0..10 active)
    const int r   = blockIdx.x * ROWS_PER_BLOCK + g;
    if (r >= B) return;

    const float* row = gs + (size_t)r * (N_AGENTS * OBS_DIM);

    // ball + team (cols 88,89,95 share one 64B line); every lane loads its own
    float bx = row[88];
    float by = row[89];
    float team = row[95];
    float g0 = bx - 1.0f;
    float bgd = sqrtf(g0 * g0 + by * by);
    bool valid = (team != 0.0f) && (bgd > 0.19f) && (bgd < 0.99f);

    // per-agent work (lanes 0..10)
    float dist = INFINITY;     // inactive lanes lose argmin
    float comb = -INFINITY;    // inactive lanes contribute exp()=0
    float qv = 0.0f;
    float gd = 0.0f;

    if (s < N_AGENTS) {
        const float* base = row + s * OBS_DIM;
        // argmax over ID block cols 97..107, first-max tie-break (strict >)
        float best = base[97];
        int bi = 0;
        #pragma unroll
        for (int j = 1; j < 11; ++j) {
            float v = base[97 + j];
            if (v > best) { best = v; bi = j; }
        }
        float px = base[2 * bi];
        float py = base[2 * bi + 1];
        float dx = px - bx, dy = py - by;
        dist = sqrtf(dx * dx + dy * dy);
        float gx = px - 1.0f;
        gd = sqrtf(gx * gx + py * py);
        qv = q[(size_t)r * N_AGENTS + s];
    }

    // ---- group argmin over dist (first-min tie-break: prefer lower index) ----
    int idx = s;
    float d = dist;
    #pragma unroll
    for (int off = 8; off >= 1; off >>= 1) {
        float d2 = __shfl_xor(d, off, TPR);
        int   i2 = __shfl_xor(idx, off, TPR);
        if (d2 < d || (d2 == d && i2 < idx)) { d = d2; idx = i2; }
    }
    // idx == holder index, uniform across the 16-lane group

    if (s < N_AGENTS) {
        comb = valid ? ((s == idx) ? 5.0f : 0.0f)
                     : 1.0f / (gd + 1e-6f);
    }

    // ---- group max of comb ----
    float m = comb;
    #pragma unroll
    for (int off = 8; off >= 1; off >>= 1)
        m = fmaxf(m, __shfl_xor(m, off, TPR));

    // ---- softmax sum + weighted q sum ----
    float w  = expf(comb - m);     // 0 for inactive lanes
    float wq = w * qv;
    #pragma unroll
    for (int off = 8; off >= 1; off >>= 1) {
        w  += __shfl_xor(w,  off, TPR);
        wq += __shfl_xor(wq, off, TPR);
    }

    if (s == 0)
        out[r] = wq * (float)N_AGENTS / w;
}

extern "C" void kernel_launch(void* const* d_in, const int* in_sizes, int n_in,
                              void* d_out, int out_size, void* d_ws, size_t ws_size,
                              hipStream_t stream) {
    const float* q  = (const float*)d_in[0];   // agents_q  [128,512,11]
    const float* gs = (const float*)d_in[1];   // global_state [128,512,1265]
    float* out = (float*)d_out;                // [128,512,1] f32

    int B = in_sizes[0] / N_AGENTS;            // 65536
    int grid = (B + ROWS_PER_BLOCK - 1) / ROWS_PER_BLOCK;  // 4096
    qmix_kernel<<<grid, 256, 0, stream>>>(q, gs, out, B);
}